// Round 5
// baseline (138.645 us; speedup 1.0000x reference)
//
#include <hip/hip_runtime.h>

// Problem dims (hardcoded per reference setup_inputs):
//   x:   (8, 64, 64, 64)  fp32
//   ref: (8, 64, 128, 128) fp32
//   out: (8, 64, 128, 128) fp32
#define B   8
#define C   64
#define HI  64
#define WI  64
#define HO  128
#define WO  128

using short8 = __attribute__((ext_vector_type(8))) short;
using f32x4  = __attribute__((ext_vector_type(4))) float;
using i32x4  = __attribute__((ext_vector_type(4))) int;

__device__ __forceinline__ float relu(float v) { return v > 0.f ? v : 0.f; }

// round-to-nearest-even f32 -> bf16 (low 16 bits of result)
__device__ __forceinline__ unsigned bf16rne(float x) {
  unsigned u = __float_as_uint(x);
  u += 0x7FFFu + ((u >> 16) & 1u);
  return u >> 16;
}
// pack two f32 -> bf16 pair (lo in bits [15:0], hi in bits [31:16])
__device__ __forceinline__ unsigned packbf(float lo, float hi) {
  unsigned ua = __float_as_uint(lo); ua += 0x7FFFu + ((ua >> 16) & 1u);
  unsigned ub = __float_as_uint(hi); ub += 0x7FFFu + ((ub >> 16) & 1u);
  return (ua >> 16) | (ub & 0xFFFF0000u);
}
// decode bf16 pair -> two f32
__device__ __forceinline__ void unpackbf(unsigned v, float& lo, float& hi) {
  lo = __uint_as_float(v << 16);
  hi = __uint_as_float(v & 0xFFFF0000u);
}

// ---------------------------------------------------------------------------
// Kernel 1 (fused pre-pass):
//   blocks [0,512):   y1 = relu(W1s @ x + bs1) via bf16 MFMA, one (b,h) row.
//                     y1 stored CHANNEL-LAST **bf16**: y1[b][h][w][ch] so
//                     k_main's 4-corner gather reads 8B per 4 channels.
//   blocks [512,640): res = channel-mean of ref, float4-vectorized (fp32 —
//                     mask compares are binary decisions, keep exact-ish)
// ---------------------------------------------------------------------------
__global__ __launch_bounds__(256) void k_pre(
    const float* __restrict__ x, const float* __restrict__ w1,
    const float* __restrict__ cb, const float* __restrict__ g,
    const float* __restrict__ bb, const float* __restrict__ mm,
    const float* __restrict__ vv, const float* __restrict__ ref,
    unsigned short* __restrict__ y1, float* __restrict__ res) {
  __shared__ __align__(16) char u_mem[17920];
  unsigned* xP = (unsigned*)u_mem;                         // [32][68] c-pair bf16
  unsigned short* W1s = (unsigned short*)(u_mem + 8704);   // [64][72] bf16
  float* yo = (float*)u_mem;                               // [64 w][68 ch] (reused after b2)
  __shared__ float s_bs1[64];

  const int tid = threadIdx.x;

  if (blockIdx.x >= 512) {           // ---- res part (HBM-bound) ----
    const int p = ((blockIdx.x - 512) * 256 + tid) * 4;
    const int b = p >> 14;           // HO*WO = 16384
    const int r = p & 16383;
    const float* pp = ref + (size_t)b * C * (HO * WO) + r;
    float4 s0 = {0.f, 0.f, 0.f, 0.f}, s1 = {0.f, 0.f, 0.f, 0.f};
#pragma unroll
    for (int c = 0; c < C; c += 2) {
      const float4 a = *(const float4*)&pp[(size_t)c * (HO * WO)];
      const float4 d = *(const float4*)&pp[(size_t)(c + 1) * (HO * WO)];
      s0.x += a.x; s0.y += a.y; s0.z += a.z; s0.w += a.w;
      s1.x += d.x; s1.y += d.y; s1.z += d.z; s1.w += d.w;
    }
    float4 o;
    o.x = (s0.x + s1.x) * (1.f / 64.f);
    o.y = (s0.y + s1.y) * (1.f / 64.f);
    o.z = (s0.z + s1.z) * (1.f / 64.f);
    o.w = (s0.w + s1.w) * (1.f / 64.f);
    *(float4*)&res[p] = o;
    return;
  }

  // ---- conv1 via MFMA ----
  const int bx = blockIdx.x;
  const int b = bx & 7;              // XCD-affine (blockIdx%8 -> XCD heuristic)
  const int h = bx >> 3;             // 0..63

  const float* xrow = x + (size_t)b * C * (HI * WI) + h * WI;
  for (int i = tid; i < 512; i += 256) {      // 32 c-pairs x 16 px-quads
    const int c2 = i >> 4, px = (i & 15) * 4;
    const float4 lo = *(const float4*)&xrow[(size_t)(2 * c2) * (HI * WI) + px];
    const float4 hi = *(const float4*)&xrow[(size_t)(2 * c2 + 1) * (HI * WI) + px];
    uint4 pk;
    pk.x = packbf(lo.x, hi.x); pk.y = packbf(lo.y, hi.y);
    pk.z = packbf(lo.z, hi.z); pk.w = packbf(lo.w, hi.w);
    *(uint4*)&xP[c2 * 68 + px] = pk;
  }
  for (int i = tid; i < 4096; i += 256) {     // W1 scale-folded -> bf16
    const int o = i >> 6;
    const float s = g[o] * rsqrtf(vv[o] + 1e-5f);
    W1s[o * 72 + (i & 63)] = (unsigned short)bf16rne(w1[i] * s);
  }
  if (tid < 64) {
    const float s = g[tid] * rsqrtf(vv[tid] + 1e-5f);
    s_bs1[tid] = cb[tid] * s + bb[tid] - mm[tid] * s;
  }
  __syncthreads();   // b1

  const int wid = tid >> 6;          // o-tile (16 o each)
  const int lane = tid & 63;
  const int lq = lane >> 4, ln = lane & 15;

  const short8 fa0 = *(const short8*)&W1s[(wid * 16 + ln) * 72 + lq * 8];       // k=0..31
  const short8 fa1 = *(const short8*)&W1s[(wid * 16 + ln) * 72 + 32 + lq * 8];  // k=32..63

  f32x4 acc[4];
#pragma unroll
  for (int t = 0; t < 4; ++t) {
    const int px = t * 16 + ln;
    i32x4 b0, b1;
#pragma unroll
    for (int r = 0; r < 4; ++r) {
      b0[r] = (int)xP[(lq * 4 + r) * 68 + px];
      b1[r] = (int)xP[(16 + lq * 4 + r) * 68 + px];
    }
    acc[t] = (f32x4){0.f, 0.f, 0.f, 0.f};
    acc[t] = __builtin_amdgcn_mfma_f32_16x16x32_bf16(fa0, __builtin_bit_cast(short8, b0), acc[t], 0, 0, 0);
    acc[t] = __builtin_amdgcn_mfma_f32_16x16x32_bf16(fa1, __builtin_bit_cast(short8, b1), acc[t], 0, 0, 0);
  }

  // D layout: o_local = lq*4 + r, w = t*16 + ln.  Remap via LDS -> [w][ch]
  const float4 bsv = *(const float4*)&s_bs1[wid * 16 + lq * 4];
  const float bs[4] = {bsv.x, bsv.y, bsv.z, bsv.w};
  __syncthreads();   // b2: xP/W1s reads done, safe to reuse u_mem
#pragma unroll
  for (int t = 0; t < 4; ++t)
#pragma unroll
    for (int r = 0; r < 4; ++r)
      yo[(t * 16 + ln) * 68 + wid * 16 + lq * 4 + r] = relu(acc[t][r] + bs[r]);
  __syncthreads();   // b3

  // pack fp32 LDS -> bf16 channel-last global  y1[b][h][w][ch]
  unsigned short* yrow = y1 + ((size_t)(b * HI + h) * WI) * 64;
  for (int i = tid; i < 512; i += 256) {      // 64 w x 8 ch-octets
    const int w = i >> 3, c8 = (i & 7) * 8;
    const float4 a = *(const float4*)&yo[w * 68 + c8];
    const float4 d = *(const float4*)&yo[w * 68 + c8 + 4];
    uint4 pk;
    pk.x = packbf(a.x, a.y); pk.y = packbf(a.z, a.w);
    pk.z = packbf(d.x, d.y); pk.w = packbf(d.z, d.w);
    *(uint4*)&yrow[w * 64 + c8] = pk;
  }
}

// ---------------------------------------------------------------------------
// Kernel 2 (main): one (b,h) full row per block; b = blockIdx&7 (XCD-affine
// so y1[b] (0.5 MB bf16) and res[b] stay L2-resident on one XCD).
//  - conv2 via bf16 MFMA (scale folded into W2s), acc kept in regs
//  - mask phase -> 4 corner weights + invden per pixel
//  - epilogue straight from acc (MFMA C-layout): y1 corners are 8B bf16x4
//    loads (channel-last), out = num*invden + relu(acc + bs2)
// ---------------------------------------------------------------------------
__global__ __launch_bounds__(256, 4) void k_main(
    const float* __restrict__ ref, const float* __restrict__ res,
    const unsigned short* __restrict__ y1, const float* __restrict__ w2,
    const float* __restrict__ cb, const float* __restrict__ g,
    const float* __restrict__ bb, const float* __restrict__ mm,
    const float* __restrict__ vv, float* __restrict__ out) {
  __shared__ __align__(16) char u_mem[26112];
  unsigned* refsP = (unsigned*)u_mem;                       // [32][132] c-pair bf16
  unsigned short* W2s = (unsigned short*)(u_mem + 16896);   // [64][72] bf16
  __shared__ float resr[3][130];
  __shared__ float s_wc[4][128];
  __shared__ float s_inv[128];
  __shared__ float s_bs[64];

  const int bx = blockIdx.x;
  const int b = bx & 7;              // XCD-affine
  const int h = bx >> 3;             // 0..127
  const int tid = threadIdx.x;

  const float* refrow = ref + (size_t)b * C * (HO * WO) + h * WO;
  for (int i = tid; i < 1024; i += 256) {     // 32 c-pairs x 32 px-quads
    const int c2 = i >> 5, px = (i & 31) * 4;
    const float4 lo = *(const float4*)&refrow[(size_t)(2 * c2) * (HO * WO) + px];
    const float4 hi = *(const float4*)&refrow[(size_t)(2 * c2 + 1) * (HO * WO) + px];
    uint4 pk;
    pk.x = packbf(lo.x, hi.x); pk.y = packbf(lo.y, hi.y);
    pk.z = packbf(lo.z, hi.z); pk.w = packbf(lo.w, hi.w);
    *(uint4*)&refsP[c2 * 132 + px] = pk;
  }
  for (int i = tid; i < 4096; i += 256) {     // W2 scale-folded -> bf16
    const int o = i >> 6;
    const float s = g[o] * rsqrtf(vv[o] + 1e-5f);
    W2s[o * 72 + (i & 63)] = (unsigned short)bf16rne(w2[i] * s);
  }
  if (tid < 64) {
    const float s = g[tid] * rsqrtf(vv[tid] + 1e-5f);
    s_bs[tid] = cb[tid] * s + bb[tid] - mm[tid] * s;
  }
  {
    const float* resb = res + (size_t)b * (HO * WO);
    for (int i = tid; i < 3 * 130; i += 256) {
      const int rr = i / 130, cc = i % 130;
      const int hh = h + rr - 1, ww = cc - 1;
      float v = 0.f;
      if (hh >= 0 && hh < HO && ww >= 0 && ww < WO)
        v = resb[hh * WO + ww];
      resr[rr][cc] = v;
    }
  }
  __syncthreads();   // b1

  // ---- MFMA conv2: 4 waves x (1 o-tile x 8 px-tiles), K=64 ----
  const int wid = tid >> 6;
  const int lane = tid & 63;
  const int lq = lane >> 4, ln = lane & 15;

  const short8 fa0 = *(const short8*)&W2s[(wid * 16 + ln) * 72 + lq * 8];
  const short8 fa1 = *(const short8*)&W2s[(wid * 16 + ln) * 72 + 32 + lq * 8];

  f32x4 acc[8];
#pragma unroll
  for (int t = 0; t < 8; ++t) {
    const int px = t * 16 + ln;
    i32x4 b0, b1;
#pragma unroll
    for (int r = 0; r < 4; ++r) {
      b0[r] = (int)refsP[(lq * 4 + r) * 132 + px];
      b1[r] = (int)refsP[(16 + lq * 4 + r) * 132 + px];
    }
    acc[t] = (f32x4){0.f, 0.f, 0.f, 0.f};
    acc[t] = __builtin_amdgcn_mfma_f32_16x16x32_bf16(fa0, __builtin_bit_cast(short8, b0), acc[t], 0, 0, 0);
    acc[t] = __builtin_amdgcn_mfma_f32_16x16x32_bf16(fa1, __builtin_bit_cast(short8, b1), acc[t], 0, 0, 0);
  }

  const int rlo = (h >= 1) ? ((h - 1) >> 1) : 0;

  // ---- mask phase: per-pixel corner weights (threads 0..127) ----
  if (tid < WO) {
    const int w = tid;
    float u[9];
#pragma unroll
    for (int dh = 0; dh < 3; ++dh)
#pragma unroll
      for (int dw = 0; dw < 3; ++dw)
        u[dh * 3 + dw] = resr[dh][w + dw];
    float sum = u[0];
#pragma unroll
    for (int k = 1; k < 9; ++k) sum += u[k];
    const float ua = sum * (1.f / 9.f);
    const bool ui = (u[4] - ua) > 0.f;

    const int clo = (w >= 1) ? ((w - 1) >> 1) : 0;
    float den = 0.f;
    float wc0 = 0.f, wc1 = 0.f, wc2 = 0.f, wc3 = 0.f;
#pragma unroll
    for (int dh = 0; dh < 3; ++dh) {
      const int hh = h + dh - 1;
      const bool hv = (hh >= 0) && (hh < HO);
      const int rs = hv ? ((hh >> 1) - rlo) : 0;
#pragma unroll
      for (int dw = 0; dw < 3; ++dw) {
        const bool up = (u[dh * 3 + dw] - ua) > 0.f;
        const float mk = (up == ui) ? 1.f : 0.f;
        den += mk;
        const int ww = w + dw - 1;
        const bool wv = (ww >= 0) && (ww < WO);
        const int cs = wv ? ((ww >> 1) - clo) : 0;
        const float t = (hv && wv) ? mk : 0.f;
        const float t0 = (rs == 0) ? t : 0.f;
        const float t1 = (rs == 1) ? t : 0.f;
        wc0 += (cs == 0) ? t0 : 0.f;
        wc1 += (cs == 1) ? t0 : 0.f;
        wc2 += (cs == 0) ? t1 : 0.f;
        wc3 += (cs == 1) ? t1 : 0.f;
      }
    }
    s_wc[0][w] = wc0; s_wc[1][w] = wc1; s_wc[2][w] = wc2; s_wc[3][w] = wc3;
    s_inv[w] = 1.f / (den + 1e-6f);
  }
  __syncthreads();   // b2: mask ready

  // ---- epilogue straight from acc: o = wid*16+lq*4+r, px = t*16+ln ----
  const int obase = wid * 16 + lq * 4;
  float bs4[4];
  *(float4*)bs4 = *(const float4*)&s_bs[obase];

  int r1 = rlo + 1; if (r1 > HI - 1) r1 = HI - 1;
  const unsigned short* y1b = y1 + (size_t)b * (HI * WI * 64);   // [h][w][ch] bf16
  const unsigned short* rowp0 = y1b + (size_t)(rlo * WI) * 64;
  const unsigned short* rowp1 = y1b + (size_t)(r1 * WI) * 64;

#pragma unroll
  for (int t = 0; t < 8; ++t) {
    const int px = t * 16 + ln;
    const int cl = (px >= 1) ? ((px - 1) >> 1) : 0;
    int c1 = cl + 1; if (c1 > WI - 1) c1 = WI - 1;
    const float wc0 = s_wc[0][px], wc1 = s_wc[1][px];
    const float wc2 = s_wc[2][px], wc3 = s_wc[3][px];
    const float inv = s_inv[px];

    const uint2 q00 = *(const uint2*)&rowp0[cl * 64 + obase];
    const uint2 q01 = *(const uint2*)&rowp0[c1 * 64 + obase];
    const uint2 q10 = *(const uint2*)&rowp1[cl * 64 + obase];
    const uint2 q11 = *(const uint2*)&rowp1[c1 * 64 + obase];

    float a00[4], a01[4], a10[4], a11[4];
    unpackbf(q00.x, a00[0], a00[1]); unpackbf(q00.y, a00[2], a00[3]);
    unpackbf(q01.x, a01[0], a01[1]); unpackbf(q01.y, a01[2], a01[3]);
    unpackbf(q10.x, a10[0], a10[1]); unpackbf(q10.y, a10[2], a10[3]);
    unpackbf(q11.x, a11[0], a11[1]); unpackbf(q11.y, a11[2], a11[3]);

    float* op = out + (size_t)(b * C + obase) * (HO * WO) + h * WO + px;
#pragma unroll
    for (int r = 0; r < 4; ++r) {
      const float n = wc0 * a00[r] + wc1 * a01[r] + wc2 * a10[r] + wc3 * a11[r];
      op[(size_t)r * (HO * WO)] = n * inv + relu(acc[t][r] + bs4[r]);
    }
  }
}

// ---------------------------------------------------------------------------
extern "C" void kernel_launch(void* const* d_in, const int* in_sizes, int n_in,
                              void* d_out, int out_size, void* d_ws, size_t ws_size,
                              hipStream_t stream) {
  (void)in_sizes; (void)n_in; (void)out_size; (void)ws_size;
  const float* x   = (const float*)d_in[0];
  const float* ref = (const float*)d_in[1];
  const float* w1  = (const float*)d_in[2];
  const float* c1b = (const float*)d_in[3];
  const float* g1  = (const float*)d_in[4];
  const float* b1  = (const float*)d_in[5];
  const float* m1  = (const float*)d_in[6];
  const float* v1  = (const float*)d_in[7];
  const float* w2  = (const float*)d_in[8];
  const float* c2b = (const float*)d_in[9];
  const float* g2  = (const float*)d_in[10];
  const float* b2  = (const float*)d_in[11];
  const float* m2  = (const float*)d_in[12];
  const float* v2  = (const float*)d_in[13];
  float* out = (float*)d_out;

  unsigned short* y1 = (unsigned short*)d_ws;              // 4 MB bf16 [b][h][w][ch]
  float* res = (float*)((char*)d_ws + (size_t)B * HI * WI * 64 * sizeof(unsigned short));  // 0.5 MB

  k_pre<<<512 + 128, 256, 0, stream>>>(x, w1, c1b, g1, b1, m1, v1, ref, y1, res);
  k_main<<<B * HO, 256, 0, stream>>>(ref, res, y1, w2, c2b, g2, b2, m2, v2, out);
}